// Round 1
// baseline (1247.711 us; speedup 1.0000x reference)
//
#include <hip/hip_runtime.h>
#include <math.h>

// ---------------------------------------------------------------------------
// ARMA GNN forward: gcn_norm -> ARMAConv(128->32,K=2,T=2,relu) -> relu ->
//                   ARMAConv(32->40,K=2,T=2) -> log_softmax
// ---------------------------------------------------------------------------

// ---- degree (count of edges arriving at col) ----
__global__ void k_deg(const int* __restrict__ col, float* __restrict__ deg, int e) {
    int i = blockIdx.x * blockDim.x + threadIdx.x;
    if (i < e) atomicAdd(&deg[col[i]], 1.0f);
}

// in-place: deg -> dinv
__global__ void k_dinv(float* __restrict__ deg, int n) {
    int i = blockIdx.x * blockDim.x + threadIdx.x;
    if (i < n) {
        float d = deg[i];
        deg[i] = (d > 0.0f) ? rsqrtf(d) : 0.0f;
    }
}

__global__ void k_ew(const int* __restrict__ row, const int* __restrict__ col,
                     const float* __restrict__ dinv, float* __restrict__ ew, int e) {
    int i = blockIdx.x * blockDim.x + threadIdx.x;
    if (i < e) ew[i] = dinv[row[i]] * dinv[col[i]];
}

// ---- fused init+root GEMM: out0 = x @ w_init, root = x @ w_root -------------
// x: [n, F_IN]; w_*: [K, F_IN, F_OUT]; outputs [n, K*F_OUT]
// block = NPB * K * F_OUT threads; thread t -> node t/(K*F_OUT), kf t%(K*F_OUT)
template<int F_IN, int F_OUT, int K, int NPB>
__global__ void k_gemm_in(const float* __restrict__ x,
                          const float* __restrict__ w_init,
                          const float* __restrict__ w_root,
                          float* __restrict__ out0,
                          float* __restrict__ root,
                          int n) {
    constexpr int KF = K * F_OUT;
    constexpr int WSZ = K * F_IN * F_OUT;
    __shared__ float ws_i[WSZ];
    __shared__ float ws_r[WSZ];
    int t = threadIdx.x;
    for (int i = t; i < WSZ; i += blockDim.x) {
        ws_i[i] = w_init[i];
        ws_r[i] = w_root[i];
    }
    __syncthreads();
    int nn   = t / KF;
    int kf   = t % KF;
    int k    = kf / F_OUT;
    int h    = kf % F_OUT;
    int node = blockIdx.x * NPB + nn;
    if (node >= n) return;
    const float* xrow = x + (long)node * F_IN;
    const float* wi = ws_i + k * F_IN * F_OUT + h;
    const float* wr = ws_r + k * F_IN * F_OUT + h;
    float acc_i = 0.0f, acc_r = 0.0f;
#pragma unroll
    for (int f = 0; f < F_IN; ++f) {
        float xv = xrow[f];                 // wave-uniform broadcast load
        acc_i += xv * wi[f * F_OUT];
        acc_r += xv * wr[f * F_OUT];
    }
    out0[(long)node * KF + kf] = acc_i;
    root[(long)node * KF + kf] = acc_r;
}

// ---- per-stack deep GEMM: out[n,k,:] = in[n,k,:] @ w[k] ---------------------
template<int F, int K, int NPB>
__global__ void k_deep(const float* __restrict__ in,
                       const float* __restrict__ w,   // [K, F, F]
                       float* __restrict__ out, int n) {
    constexpr int KF = K * F;
    constexpr int WSZ = K * F * F;
    __shared__ float ws[WSZ];
    int t = threadIdx.x;
    for (int i = t; i < WSZ; i += blockDim.x) ws[i] = w[i];
    __syncthreads();
    int nn   = t / KF;
    int kf   = t % KF;
    int k    = kf / F;
    int h    = kf % F;
    int node = blockIdx.x * NPB + nn;
    if (node >= n) return;
    const float* irow = in + (long)node * KF + k * F;
    const float* wk = ws + k * F * F + h;
    float acc = 0.0f;
#pragma unroll
    for (int f = 0; f < F; ++f) acc += irow[f] * wk[f * F];
    out[(long)node * KF + kf] = acc;
}

// ---- B = root + b (broadcast bias) -----------------------------------------
template<int KF>
__global__ void k_init_acc(const float* __restrict__ root,
                           const float* __restrict__ b,
                           float* __restrict__ B, int total) {
    int i = blockIdx.x * blockDim.x + threadIdx.x;
    if (i < total) B[i] = root[i] + b[i % KF];
}

// ---- scatter: B[col[e]*KF + kf] += A[row[e]*KF + kf] * ew[e] ----------------
template<int KF>
__global__ void k_scatter(const float* __restrict__ A,
                          const int* __restrict__ row,
                          const int* __restrict__ col,
                          const float* __restrict__ ew,
                          float* __restrict__ B, int e) {
    long idx = (long)blockIdx.x * blockDim.x + threadIdx.x;
    int  ed  = (int)(idx / KF);
    int  kf  = (int)(idx % KF);
    if (ed >= e) return;
    float w = ew[ed];
    int r = row[ed], c = col[ed];
    atomicAdd(&B[(long)c * KF + kf], A[(long)r * KF + kf] * w);
}

__global__ void k_relu(float* __restrict__ B, int total) {
    int i = blockIdx.x * blockDim.x + threadIdx.x;
    if (i < total) B[i] = fmaxf(B[i], 0.0f);
}

// ---- conv1 epilogue: per-stack relu then mean over K (then outer relu) -----
__global__ void k_mean_relu(const float* __restrict__ B, float* __restrict__ h, int n) {
    int i = blockIdx.x * blockDim.x + threadIdx.x;
    if (i < n * 32) {
        int node = i / 32, f = i % 32;
        float a = fmaxf(B[(long)node * 64 + f], 0.0f);
        float c = fmaxf(B[(long)node * 64 + 32 + f], 0.0f);
        h[i] = 0.5f * (a + c);   // >=0 already, outer relu is a no-op
    }
}

// ---- conv2 epilogue: mean over K + row log_softmax (40 classes) ------------
__global__ void k_logsoftmax(const float* __restrict__ B, float* __restrict__ out, int n) {
    int gid  = blockIdx.x * blockDim.x + threadIdx.x;
    int wave = gid >> 6;
    int lane = gid & 63;
    if (wave >= n) return;
    float v = -INFINITY;
    if (lane < 40)
        v = 0.5f * (B[(long)wave * 80 + lane] + B[(long)wave * 80 + 40 + lane]);
    float m = v;
#pragma unroll
    for (int o = 32; o; o >>= 1) m = fmaxf(m, __shfl_xor(m, o));
    float ex = (lane < 40) ? expf(v - m) : 0.0f;
    float s = ex;
#pragma unroll
    for (int o = 32; o; o >>= 1) s += __shfl_xor(s, o);
    if (lane < 40) out[(long)wave * 40 + lane] = v - m - logf(s);
}

// ---------------------------------------------------------------------------
extern "C" void kernel_launch(void* const* d_in, const int* in_sizes, int n_in,
                              void* d_out, int out_size, void* d_ws, size_t ws_size,
                              hipStream_t stream) {
    const float* x       = (const float*)d_in[0];
    const int*   eidx    = (const int*)d_in[1];
    const float* w1_init = (const float*)d_in[2];
    const float* w1_deep = (const float*)d_in[3];
    const float* w1_root = (const float*)d_in[4];
    const float* b1      = (const float*)d_in[5];
    const float* w2_init = (const float*)d_in[6];
    const float* w2_deep = (const float*)d_in[7];
    const float* w2_root = (const float*)d_in[8];
    const float* b2      = (const float*)d_in[9];
    float* out = (float*)d_out;

    const int N = in_sizes[0] / 128;
    const int E = in_sizes[1] / 2;
    const int* row = eidx;
    const int* col = eidx + E;

    // workspace layout (floats)
    float* ws   = (float*)d_ws;
    float* dinv = ws;                 // N   (deg, then dinv in-place)
    float* ew   = dinv + N;           // E
    float* A    = ew + E;             // N*80
    float* B    = A + (long)N * 80;   // N*80
    float* root = B + (long)N * 80;   // N*80
    float* h    = root + (long)N * 80;// N*32

    const int BS = 256;
    auto cdiv = [](long a, long b) { return (int)((a + b - 1) / b); };

    // ---- edge norm ----
    hipMemsetAsync(dinv, 0, (size_t)N * 4, stream);
    k_deg<<<cdiv(E, BS), BS, 0, stream>>>(col, dinv, E);
    k_dinv<<<cdiv(N, BS), BS, 0, stream>>>(dinv, N);
    k_ew<<<cdiv(E, BS), BS, 0, stream>>>(row, col, dinv, ew, E);

    // ---- conv1: 128 -> 32, K=2 (KF=64), relu ----
    k_gemm_in<128, 32, 2, 4><<<cdiv(N, 4), 4 * 64, 0, stream>>>(x, w1_init, w1_root, A, root, N);
    // t = 0
    k_init_acc<64><<<cdiv((long)N * 64, BS), BS, 0, stream>>>(root, b1, B, N * 64);
    k_scatter<64><<<cdiv((long)E * 64, BS), BS, 0, stream>>>(A, row, col, ew, B, E);
    k_relu<<<cdiv((long)N * 64, BS), BS, 0, stream>>>(B, N * 64);
    // t = 1
    k_deep<32, 2, 4><<<cdiv(N, 4), 4 * 64, 0, stream>>>(B, w1_deep, A, N);
    k_init_acc<64><<<cdiv((long)N * 64, BS), BS, 0, stream>>>(root, b1, B, N * 64);
    k_scatter<64><<<cdiv((long)E * 64, BS), BS, 0, stream>>>(A, row, col, ew, B, E);
    k_mean_relu<<<cdiv((long)N * 32, BS), BS, 0, stream>>>(B, h, N);

    // ---- conv2: 32 -> 40, K=2 (KF=80), no act ----
    k_gemm_in<32, 40, 2, 4><<<cdiv(N, 4), 4 * 80, 0, stream>>>(h, w2_init, w2_root, A, root, N);
    // t = 0
    k_init_acc<80><<<cdiv((long)N * 80, BS), BS, 0, stream>>>(root, b2, B, N * 80);
    k_scatter<80><<<cdiv((long)E * 80, BS), BS, 0, stream>>>(A, row, col, ew, B, E);
    // t = 1
    k_deep<40, 2, 4><<<cdiv(N, 4), 4 * 80, 0, stream>>>(B, w2_deep, A, N);
    k_init_acc<80><<<cdiv((long)N * 80, BS), BS, 0, stream>>>(root, b2, B, N * 80);
    k_scatter<80><<<cdiv((long)E * 80, BS), BS, 0, stream>>>(A, row, col, ew, B, E);
    // epilogue: mean over K + log_softmax
    k_logsoftmax<<<cdiv((long)N * 64, BS), BS, 0, stream>>>(B, out, N);
}

// Round 4
// 708.677 us; speedup vs baseline: 1.7606x; 1.7606x over previous
//
#include <hip/hip_runtime.h>
#include <math.h>

// ---------------------------------------------------------------------------
// ARMA GNN forward: gcn_norm -> ARMAConv(128->32,K=2,T=2,relu) -> relu ->
//                   ARMAConv(32->40,K=2,T=2) -> log_softmax
// Propagation via CSC gather (counting-sorted edges), no atomics in hot loop.
// ---------------------------------------------------------------------------

__global__ void k_hist(const int* __restrict__ col, int* __restrict__ deg, int e) {
    int i = blockIdx.x * blockDim.x + threadIdx.x;
    if (i < e) atomicAdd(&deg[col[i]], 1);
}

__global__ void k_dinv(const int* __restrict__ deg, float* __restrict__ dinv, int n) {
    int i = blockIdx.x * blockDim.x + threadIdx.x;
    if (i < n) {
        int d = deg[i];
        dinv[i] = d > 0 ? rsqrtf((float)d) : 0.0f;
    }
}

// exclusive scan, stage 1: per-block (256 elems), partial exclusive + block sums
__global__ void k_scan1(const int* __restrict__ deg, int* __restrict__ start,
                        int* __restrict__ bsum, int n) {
    __shared__ int s[256];
    int t = threadIdx.x, idx = blockIdx.x * 256 + t;
    int v = (idx < n) ? deg[idx] : 0;
    s[t] = v; __syncthreads();
    for (int o = 1; o < 256; o <<= 1) {
        int x = (t >= o) ? s[t - o] : 0;
        __syncthreads(); s[t] += x; __syncthreads();
    }
    if (idx <= n) start[idx] = s[t] - v;   // exclusive within block
    if (t == 255) bsum[blockIdx.x] = s[255];
}

// stage 2: exclusive scan of the 256 block sums
__global__ void k_scan2(const int* __restrict__ bsum, int* __restrict__ bscan) {
    __shared__ int s[256];
    int t = threadIdx.x;
    int v = bsum[t]; s[t] = v; __syncthreads();
    for (int o = 1; o < 256; o <<= 1) {
        int x = (t >= o) ? s[t - o] : 0;
        __syncthreads(); s[t] += x; __syncthreads();
    }
    bscan[t] = s[t] - v;
}

// stage 3: add block offsets; also init cursor = start
__global__ void k_scan3(int* __restrict__ start, int* __restrict__ cursor,
                        const int* __restrict__ bscan, int n) {
    int idx = blockIdx.x * 256 + threadIdx.x;
    if (idx <= n) {
        int v = start[idx] + bscan[idx >> 8];
        start[idx] = v;
        if (idx < n) cursor[idx] = v;
    }
}

// bucket-scatter edges by col; pack (row, ew) into int2
__global__ void k_sort(const int* __restrict__ row, const int* __restrict__ col,
                       const float* __restrict__ dinv, int* __restrict__ cursor,
                       int2* __restrict__ sedge, int e) {
    int i = blockIdx.x * blockDim.x + threadIdx.x;
    if (i < e) {
        int r = row[i], c = col[i];
        int pos = atomicAdd(&cursor[c], 1);
        sedge[pos] = make_int2(r, __float_as_int(dinv[r] * dinv[c]));
    }
}

// ---- fused init+root GEMM: out0 = x @ w_init, root = x @ w_root -------------
template<int F_IN, int F_OUT, int K, int NPB>
__global__ void k_gemm_in(const float* __restrict__ x,
                          const float* __restrict__ w_init,
                          const float* __restrict__ w_root,
                          float* __restrict__ out0,
                          float* __restrict__ root,
                          int n) {
    constexpr int KF = K * F_OUT;
    constexpr int WSZ = K * F_IN * F_OUT;
    __shared__ float ws_i[WSZ];
    __shared__ float ws_r[WSZ];
    int t = threadIdx.x;
    for (int i = t; i < WSZ; i += blockDim.x) {
        ws_i[i] = w_init[i];
        ws_r[i] = w_root[i];
    }
    __syncthreads();
    int nn   = t / KF;
    int kf   = t % KF;
    int k    = kf / F_OUT;
    int h    = kf % F_OUT;
    int node = blockIdx.x * NPB + nn;
    if (node >= n) return;
    const float* xrow = x + (long)node * F_IN;
    const float* wi = ws_i + k * F_IN * F_OUT + h;
    const float* wr = ws_r + k * F_IN * F_OUT + h;
    float acc_i = 0.0f, acc_r = 0.0f;
#pragma unroll
    for (int f = 0; f < F_IN; ++f) {
        float xv = xrow[f];
        acc_i += xv * wi[f * F_OUT];
        acc_r += xv * wr[f * F_OUT];
    }
    out0[(long)node * KF + kf] = acc_i;
    root[(long)node * KF + kf] = acc_r;
}

// ---- per-stack deep GEMM: out[n,k,:] = in[n,k,:] @ w[k] ---------------------
template<int F, int K, int NPB>
__global__ void k_deep(const float* __restrict__ in,
                       const float* __restrict__ w,   // [K, F, F]
                       float* __restrict__ out, int n) {
    constexpr int KF = K * F;
    constexpr int WSZ = K * F * F;
    __shared__ float ws[WSZ];
    int t = threadIdx.x;
    for (int i = t; i < WSZ; i += blockDim.x) ws[i] = w[i];
    __syncthreads();
    int nn   = t / KF;
    int kf   = t % KF;
    int k    = kf / F;
    int h    = kf % F;
    int node = blockIdx.x * NPB + nn;
    if (node >= n) return;
    const float* irow = in + (long)node * KF + k * F;
    const float* wk = ws + k * F * F + h;
    float acc = 0.0f;
#pragma unroll
    for (int f = 0; f < F; ++f) acc += irow[f] * wk[f * F];
    out[(long)node * KF + kf] = acc;
}

// ---- CSC gather: out[n,kf] = root[n,kf] + b[kf] + sum_in A[row,kf]*w --------
// MODE 0: plain store; MODE 1: relu; MODE 2: per-stack relu then mean over K=2
// (KF=64, writes [n,32]; requires blockDim%64==0 so lane==kf)
template<int KF, int MODE>
__global__ void k_gather(const float* __restrict__ A, const int2* __restrict__ sedge,
                         const int* __restrict__ start, const float* __restrict__ root,
                         const float* __restrict__ bias, float* __restrict__ out, int n) {
    int gid = blockIdx.x * blockDim.x + threadIdx.x;
    int node = gid / KF, kf = gid % KF;
    if (node >= n) return;
    int s0 = start[node], s1 = start[node + 1];
    float acc = root[(long)node * KF + kf] + bias[kf];
    int e = s0;
    for (; e + 2 <= s1; e += 2) {
        int2 p0 = sedge[e], p1 = sedge[e + 1];
        acc += A[(long)p0.x * KF + kf] * __int_as_float(p0.y);
        acc += A[(long)p1.x * KF + kf] * __int_as_float(p1.y);
    }
    if (e < s1) {
        int2 p = sedge[e];
        acc += A[(long)p.x * KF + kf] * __int_as_float(p.y);
    }
    if (MODE == 0) {
        out[(long)node * KF + kf] = acc;
    } else if (MODE == 1) {
        out[(long)node * KF + kf] = fmaxf(acc, 0.0f);
    } else {
        float v = fmaxf(acc, 0.0f);
        float o2 = __shfl_xor(v, 32);
        if (kf < 32) out[(long)node * 32 + kf] = 0.5f * (v + o2);
    }
}

// ---- conv2 epilogue: mean over K + row log_softmax (40 classes) ------------
__global__ void k_logsoftmax(const float* __restrict__ B, float* __restrict__ out, int n) {
    int gid  = blockIdx.x * blockDim.x + threadIdx.x;
    int wave = gid >> 6;
    int lane = gid & 63;
    if (wave >= n) return;
    float v = -INFINITY;
    if (lane < 40)
        v = 0.5f * (B[(long)wave * 80 + lane] + B[(long)wave * 80 + 40 + lane]);
    float m = v;
#pragma unroll
    for (int o = 32; o; o >>= 1) m = fmaxf(m, __shfl_xor(m, o));
    float ex = (lane < 40) ? expf(v - m) : 0.0f;
    float s = ex;
#pragma unroll
    for (int o = 32; o; o >>= 1) s += __shfl_xor(s, o);
    if (lane < 40) out[(long)wave * 40 + lane] = v - m - logf(s);
}

// ---------------------------------------------------------------------------
extern "C" void kernel_launch(void* const* d_in, const int* in_sizes, int n_in,
                              void* d_out, int out_size, void* d_ws, size_t ws_size,
                              hipStream_t stream) {
    const float* x       = (const float*)d_in[0];
    const int*   eidx    = (const int*)d_in[1];
    const float* w1_init = (const float*)d_in[2];
    const float* w1_deep = (const float*)d_in[3];
    const float* w1_root = (const float*)d_in[4];
    const float* b1      = (const float*)d_in[5];
    const float* w2_init = (const float*)d_in[6];
    const float* w2_deep = (const float*)d_in[7];
    const float* w2_root = (const float*)d_in[8];
    const float* b2      = (const float*)d_in[9];
    float* out = (float*)d_out;

    const int N = in_sizes[0] / 128;
    const int E = in_sizes[1] / 2;
    const int* row = eidx;
    const int* col = eidx + E;

    // workspace layout (persist first, transients after; h aliases B)
    int2*  sedge  = (int2*)d_ws;                 // E
    int*   start  = (int*)(sedge + E);           // N+1
    float* A      = (float*)(start + N + 1);     // N*80
    float* B      = A + (long)N * 80;            // N*80
    float* root   = B + (long)N * 80;            // N*80
    int*   deg_i  = (int*)(root + (long)N * 80); // N   (transient)
    int*   cursor = deg_i + N;                   // N   (transient)
    int*   bsum   = cursor + N;                  // 256 (transient)
    int*   bscan  = bsum + 256;                  // 256 (transient)
    float* dinv   = (float*)(bscan + 256);       // N   (transient)
    float* h      = B;                           // N*32, aliases B (safe: see order)

    const int BS = 256;
    auto cdiv = [](long a, long b) { return (int)((a + b - 1) / b); };

    // ---- CSC build: histogram -> scan -> bucket scatter ----
    hipMemsetAsync(deg_i, 0, (size_t)N * 4, stream);
    k_hist<<<cdiv(E, BS), BS, 0, stream>>>(col, deg_i, E);
    k_dinv<<<cdiv(N, BS), BS, 0, stream>>>(deg_i, dinv, N);
    k_scan1<<<256, 256, 0, stream>>>(deg_i, start, bsum, N);
    k_scan2<<<1, 256, 0, stream>>>(bsum, bscan);
    k_scan3<<<256, 256, 0, stream>>>(start, cursor, bscan, N);
    k_sort<<<cdiv(E, BS), BS, 0, stream>>>(row, col, dinv, cursor, sedge, E);

    // ---- conv1: 128 -> 32, K=2 (KF=64), relu ----
    k_gemm_in<128, 32, 2, 4><<<cdiv(N, 4), 4 * 64, 0, stream>>>(x, w1_init, w1_root, A, root, N);
    k_gather<64, 1><<<cdiv((long)N * 64, BS), BS, 0, stream>>>(A, sedge, start, root, b1, B, N);
    k_deep<32, 2, 4><<<cdiv(N, 4), 4 * 64, 0, stream>>>(B, w1_deep, A, N);
    k_gather<64, 2><<<cdiv((long)N * 64, BS), BS, 0, stream>>>(A, sedge, start, root, b1, h, N);

    // ---- conv2: 32 -> 40, K=2 (KF=80), no act ----
    k_gemm_in<32, 40, 2, 4><<<cdiv(N, 4), 4 * 80, 0, stream>>>(h, w2_init, w2_root, A, root, N);
    k_gather<80, 0><<<cdiv((long)N * 80, 320), 320, 0, stream>>>(A, sedge, start, root, b2, B, N);
    k_deep<40, 2, 4><<<cdiv(N, 4), 4 * 80, 0, stream>>>(B, w2_deep, A, N);
    k_gather<80, 0><<<cdiv((long)N * 80, 320), 320, 0, stream>>>(A, sedge, start, root, b2, B, N);

    // ---- epilogue: mean over K + log_softmax ----
    k_logsoftmax<<<cdiv((long)N * 64, BS), BS, 0, stream>>>(B, out, N);
}

// Round 5
// 594.254 us; speedup vs baseline: 2.0996x; 1.1925x over previous
//
#include <hip/hip_runtime.h>
#include <math.h>

// ---------------------------------------------------------------------------
// ARMA GNN forward: gcn_norm -> ARMAConv(128->32,K=2,T=2,relu) -> relu ->
//                   ARMAConv(32->40,K=2,T=2) -> log_softmax
// Propagation via CSC gather (counting-sorted edges), no atomics in hot loop.
// ---------------------------------------------------------------------------

__global__ void k_hist(const int* __restrict__ col, int* __restrict__ deg, int e) {
    int i = blockIdx.x * blockDim.x + threadIdx.x;
    if (i < e) atomicAdd(&deg[col[i]], 1);
}

__global__ void k_dinv(const int* __restrict__ deg, float* __restrict__ dinv, int n) {
    int i = blockIdx.x * blockDim.x + threadIdx.x;
    if (i < n) {
        int d = deg[i];
        dinv[i] = d > 0 ? rsqrtf((float)d) : 0.0f;
    }
}

// exclusive scan, stage 1: per-block (256 elems), partial exclusive + block sums
__global__ void k_scan1(const int* __restrict__ deg, int* __restrict__ start,
                        int* __restrict__ bsum, int n) {
    __shared__ int s[256];
    int t = threadIdx.x, idx = blockIdx.x * 256 + t;
    int v = (idx < n) ? deg[idx] : 0;
    s[t] = v; __syncthreads();
    for (int o = 1; o < 256; o <<= 1) {
        int x = (t >= o) ? s[t - o] : 0;
        __syncthreads(); s[t] += x; __syncthreads();
    }
    if (idx <= n) start[idx] = s[t] - v;   // exclusive within block
    if (t == 255) bsum[blockIdx.x] = s[255];
}

// stage 2: exclusive scan of the 256 block sums
__global__ void k_scan2(const int* __restrict__ bsum, int* __restrict__ bscan) {
    __shared__ int s[256];
    int t = threadIdx.x;
    int v = bsum[t]; s[t] = v; __syncthreads();
    for (int o = 1; o < 256; o <<= 1) {
        int x = (t >= o) ? s[t - o] : 0;
        __syncthreads(); s[t] += x; __syncthreads();
    }
    bscan[t] = s[t] - v;
}

// stage 3: add block offsets; also init cursor = start
__global__ void k_scan3(int* __restrict__ start, int* __restrict__ cursor,
                        const int* __restrict__ bscan, int n) {
    int idx = blockIdx.x * 256 + threadIdx.x;
    if (idx <= n) {
        int v = start[idx] + bscan[idx >> 8];
        start[idx] = v;
        if (idx < n) cursor[idx] = v;
    }
}

// bucket-scatter edges by col; pack (row, ew) into int2
__global__ void k_sort(const int* __restrict__ row, const int* __restrict__ col,
                       const float* __restrict__ dinv, int* __restrict__ cursor,
                       int2* __restrict__ sedge, int e) {
    int i = blockIdx.x * blockDim.x + threadIdx.x;
    if (i < e) {
        int r = row[i], c = col[i];
        int pos = atomicAdd(&cursor[c], 1);
        sedge[pos] = make_int2(r, __float_as_int(dinv[r] * dinv[c]));
    }
}

// ---- fused init+root GEMM: out0 = x @ w_init, root = x @ w_root -------------
// NPB*KF threads per block; weights staged in LDS, amortized over NPB nodes.
template<int F_IN, int F_OUT, int K, int NPB>
__global__ void k_gemm_in(const float* __restrict__ x,
                          const float* __restrict__ w_init,
                          const float* __restrict__ w_root,
                          float* __restrict__ out0,
                          float* __restrict__ root,
                          int n) {
    constexpr int KF = K * F_OUT;
    constexpr int WSZ = K * F_IN * F_OUT;
    __shared__ float ws_i[WSZ];
    __shared__ float ws_r[WSZ];
    int t = threadIdx.x;
    for (int i = t; i < WSZ; i += blockDim.x) {
        ws_i[i] = w_init[i];
        ws_r[i] = w_root[i];
    }
    __syncthreads();
    int nn   = t / KF;
    int kf   = t % KF;
    int k    = kf / F_OUT;
    int h    = kf % F_OUT;
    int node = blockIdx.x * NPB + nn;
    if (node >= n) return;
    const float* xrow = x + (long)node * F_IN;
    const float* wi = ws_i + k * F_IN * F_OUT + h;
    const float* wr = ws_r + k * F_IN * F_OUT + h;
    float acc_i = 0.0f, acc_r = 0.0f;
#pragma unroll
    for (int f = 0; f < F_IN; ++f) {
        float xv = xrow[f];
        acc_i += xv * wi[f * F_OUT];
        acc_r += xv * wr[f * F_OUT];
    }
    out0[(long)node * KF + kf] = acc_i;
    root[(long)node * KF + kf] = acc_r;
}

// ---- per-stack deep GEMM: out[n,k,:] = in[n,k,:] @ w[k] ---------------------
template<int F, int K, int NPB>
__global__ void k_deep(const float* __restrict__ in,
                       const float* __restrict__ w,   // [K, F, F]
                       float* __restrict__ out, int n) {
    constexpr int KF = K * F;
    constexpr int WSZ = K * F * F;
    __shared__ float ws[WSZ];
    int t = threadIdx.x;
    for (int i = t; i < WSZ; i += blockDim.x) ws[i] = w[i];
    __syncthreads();
    int nn   = t / KF;
    int kf   = t % KF;
    int k    = kf / F;
    int h    = kf % F;
    int node = blockIdx.x * NPB + nn;
    if (node >= n) return;
    const float* irow = in + (long)node * KF + k * F;
    const float* wk = ws + k * F * F + h;
    float acc = 0.0f;
#pragma unroll
    for (int f = 0; f < F; ++f) acc += irow[f] * wk[f * F];
    out[(long)node * KF + kf] = acc;
}

// ---- CSC gather: out[n,kf] = root[n,kf] + b[kf] + sum_in A[row,kf]*w --------
// MODE 0: plain store; MODE 1: relu; MODE 2: per-stack relu then mean over K=2
// (KF=64, writes [n,32]; requires blockDim%64==0 so lane==kf)
template<int KF, int MODE>
__global__ void k_gather(const float* __restrict__ A, const int2* __restrict__ sedge,
                         const int* __restrict__ start, const float* __restrict__ root,
                         const float* __restrict__ bias, float* __restrict__ out, int n) {
    int gid = blockIdx.x * blockDim.x + threadIdx.x;
    int node = gid / KF, kf = gid % KF;
    if (node >= n) return;
    int s0 = start[node], s1 = start[node + 1];
    float acc = root[(long)node * KF + kf] + bias[kf];
    int e = s0;
    for (; e + 2 <= s1; e += 2) {
        int2 p0 = sedge[e], p1 = sedge[e + 1];
        acc += A[(long)p0.x * KF + kf] * __int_as_float(p0.y);
        acc += A[(long)p1.x * KF + kf] * __int_as_float(p1.y);
    }
    if (e < s1) {
        int2 p = sedge[e];
        acc += A[(long)p.x * KF + kf] * __int_as_float(p.y);
    }
    if (MODE == 0) {
        out[(long)node * KF + kf] = acc;
    } else if (MODE == 1) {
        out[(long)node * KF + kf] = fmaxf(acc, 0.0f);
    } else {
        float v = fmaxf(acc, 0.0f);
        float o2 = __shfl_xor(v, 32);
        if (kf < 32) out[(long)node * 32 + kf] = 0.5f * (v + o2);
    }
}

// ---- conv2 epilogue: mean over K + row log_softmax (40 classes) ------------
__global__ void k_logsoftmax(const float* __restrict__ B, float* __restrict__ out, int n) {
    int gid  = blockIdx.x * blockDim.x + threadIdx.x;
    int wave = gid >> 6;
    int lane = gid & 63;
    if (wave >= n) return;
    float v = -INFINITY;
    if (lane < 40)
        v = 0.5f * (B[(long)wave * 80 + lane] + B[(long)wave * 80 + 40 + lane]);
    float m = v;
#pragma unroll
    for (int o = 32; o; o >>= 1) m = fmaxf(m, __shfl_xor(m, o));
    float ex = (lane < 40) ? expf(v - m) : 0.0f;
    float s = ex;
#pragma unroll
    for (int o = 32; o; o >>= 1) s += __shfl_xor(s, o);
    if (lane < 40) out[(long)wave * 40 + lane] = v - m - logf(s);
}

// ---------------------------------------------------------------------------
extern "C" void kernel_launch(void* const* d_in, const int* in_sizes, int n_in,
                              void* d_out, int out_size, void* d_ws, size_t ws_size,
                              hipStream_t stream) {
    const float* x       = (const float*)d_in[0];
    const int*   eidx    = (const int*)d_in[1];
    const float* w1_init = (const float*)d_in[2];
    const float* w1_deep = (const float*)d_in[3];
    const float* w1_root = (const float*)d_in[4];
    const float* b1      = (const float*)d_in[5];
    const float* w2_init = (const float*)d_in[6];
    const float* w2_deep = (const float*)d_in[7];
    const float* w2_root = (const float*)d_in[8];
    const float* b2      = (const float*)d_in[9];
    float* out = (float*)d_out;

    const int N = in_sizes[0] / 128;
    const int E = in_sizes[1] / 2;
    const int* row = eidx;
    const int* col = eidx + E;

    // workspace layout (persist first, transients after; h aliases B)
    int2*  sedge  = (int2*)d_ws;                 // E
    int*   start  = (int*)(sedge + E);           // N+1
    float* A      = (float*)(start + N + 1);     // N*80
    float* B      = A + (long)N * 80;            // N*80
    float* root   = B + (long)N * 80;            // N*80
    int*   deg_i  = (int*)(root + (long)N * 80); // N   (transient)
    int*   cursor = deg_i + N;                   // N   (transient)
    int*   bsum   = cursor + N;                  // 256 (transient)
    int*   bscan  = bsum + 256;                  // 256 (transient)
    float* dinv   = (float*)(bscan + 256);       // N   (transient)
    float* h      = B;                           // N*32, aliases B (safe: see order)

    const int BS = 256;
    auto cdiv = [](long a, long b) { return (int)((a + b - 1) / b); };

    // ---- CSC build: histogram -> scan -> bucket scatter ----
    hipMemsetAsync(deg_i, 0, (size_t)N * 4, stream);
    k_hist<<<cdiv(E, BS), BS, 0, stream>>>(col, deg_i, E);
    k_dinv<<<cdiv(N, BS), BS, 0, stream>>>(deg_i, dinv, N);
    k_scan1<<<256, 256, 0, stream>>>(deg_i, start, bsum, N);
    k_scan2<<<1, 256, 0, stream>>>(bsum, bscan);
    k_scan3<<<256, 256, 0, stream>>>(start, cursor, bscan, N);
    k_sort<<<cdiv(E, BS), BS, 0, stream>>>(row, col, dinv, cursor, sedge, E);

    // ---- conv1: 128 -> 32, K=2 (KF=64), relu ----
    // NPB=16: block=1024 (16 waves), 64KB LDS -> 2 blocks/CU = 32 waves = 100% occ,
    // and 4x fewer blocks -> 4x less weight-staging traffic vs NPB=4.
    k_gemm_in<128, 32, 2, 16><<<cdiv(N, 16), 16 * 64, 0, stream>>>(x, w1_init, w1_root, A, root, N);
    k_gather<64, 1><<<cdiv((long)N * 64, BS), BS, 0, stream>>>(A, sedge, start, root, b1, B, N);
    k_deep<32, 2, 16><<<cdiv(N, 16), 16 * 64, 0, stream>>>(B, w1_deep, A, N);
    k_gather<64, 2><<<cdiv((long)N * 64, BS), BS, 0, stream>>>(A, sedge, start, root, b1, h, N);

    // ---- conv2: 32 -> 40, K=2 (KF=80), no act ----
    // NPB=8: block=640 (10 waves); LDS small; 3 blocks/CU = 30 waves = 94% occ.
    k_gemm_in<32, 40, 2, 8><<<cdiv(N, 8), 8 * 80, 0, stream>>>(h, w2_init, w2_root, A, root, N);
    k_gather<80, 0><<<cdiv((long)N * 80, 320), 320, 0, stream>>>(A, sedge, start, root, b2, B, N);
    k_deep<40, 2, 8><<<cdiv(N, 8), 8 * 80, 0, stream>>>(B, w2_deep, A, N);
    k_gather<80, 0><<<cdiv((long)N * 80, 320), 320, 0, stream>>>(A, sedge, start, root, b2, B, N);

    // ---- epilogue: mean over K + log_softmax ----
    k_logsoftmax<<<cdiv((long)N * 64, BS), BS, 0, stream>>>(B, out, N);
}